// Round 9
// baseline (201.452 us; speedup 1.0000x reference)
//
#include <hip/hip_runtime.h>
#include <math.h>

#define NG 5
#define NF 5
#define NR 5
#define NW 4
#define STEP 16          // 1 + NG + NF + NR
#define M_OTH 15         // NG + NF + NR
#define NB 60            // NW * M_OTH
#define L 512            // MAXLEN
#define FEAT 64
#define GAMMA 5.0f
#define SEGN 11          // STEP - NR
#define NSEG 44          // NW * SEGN
#define SEGD 32768       // MAXLEN * FEAT

#define C1   0.28853900817779268f   // 1/(GAMMA*ln2)
#define GLN2 3.4657359027997265f    // GAMMA*ln2
#define BIGS 2.8853900e9f           // 1e10*C1 (acts as +inf in scaled domain)
#define BNDW 1056                   // boundary slots (max touched idx ~1037)
#define NTIER 7
#define GRAM_BLK0 60
#define SENT 0x7FC000007FC00000ULL  // NaN in both halves

typedef struct __align__(16) { unsigned long long x, y; } ull2_t;

// ---------------------------------------------------------------------------
// K1: pairwise sqdist, 128x128 tiles, norm-form, R=1-skewed mod-512 layout,
// pre-scaled by C1:  DS[b][(jj + ii) & 511][ii] = C1*dist(anchor_ii, other_jj)
// With this skew, lane G (row ii=G) at DP step t reads [t & 511][G]: each
// wave's 64 lanes read 256 contiguous bytes per step.
// Tiles with ti>=la or tj>=lb skipped (provably never reach the capture cell).
// ---------------------------------------------------------------------------
__global__ __launch_bounds__(256, 2) void sqdist_kernel(const float* __restrict__ data,
                                                        const int* __restrict__ lens,
                                                        float* __restrict__ DS) {
    int b = blockIdx.z;
    int w = b / M_OTH, m = b % M_OTH;
    int la = lens[w * STEP];
    int lb = lens[w * STEP + 1 + m];
    int ti = blockIdx.y * 128;
    int tj = blockIdx.x * 128;
    if (ti >= la || tj >= lb) return;            // never consumed

    const float* X = data + (size_t)(w * STEP) * L * FEAT;            // anchor (i)
    const float* Y = data + (size_t)(w * STEP + 1 + m) * L * FEAT;    // other (j)

    __shared__ float Xs[128][68];
    __shared__ float Ys[128][68];
    __shared__ float nx[128], ny[128];

    int t = threadIdx.y * 16 + threadIdx.x;
    #pragma unroll
    for (int k = 0; k < 8; ++k) {
        int idx = t + k * 256;
        int r = idx >> 4, c = (idx & 15) * 4;
        *(float4*)&Xs[r][c] = *(const float4*)(X + (size_t)(ti + r) * FEAT + c);
        *(float4*)&Ys[r][c] = *(const float4*)(Y + (size_t)(tj + r) * FEAT + c);
    }
    __syncthreads();
    {   // row norms
        int r = t & 127;
        const float* row = (t < 128) ? Xs[r] : Ys[r];
        float s = 0.f;
        #pragma unroll
        for (int f = 0; f < 64; f += 4) {
            float4 v = *(const float4*)&row[f];
            s += v.x * v.x + v.y * v.y + v.z * v.z + v.w * v.w;
        }
        if (t < 128) nx[r] = s; else ny[r] = s;
    }
    __syncthreads();

    int tx = threadIdx.x, ty = threadIdx.y;   // ii = 16a+tx, jj = 16c+ty (strided)
    float acc[8][8] = {};
    for (int f = 0; f < 64; f += 4) {
        float4 xv[8], yv[8];
        #pragma unroll
        for (int a = 0; a < 8; ++a) xv[a] = *(const float4*)&Xs[16 * a + tx][f];
        #pragma unroll
        for (int c = 0; c < 8; ++c) yv[c] = *(const float4*)&Ys[16 * c + ty][f];
        #pragma unroll
        for (int a = 0; a < 8; ++a)
            #pragma unroll
            for (int c = 0; c < 8; ++c)
                acc[a][c] += xv[a].x * yv[c].x + xv[a].y * yv[c].y +
                             xv[a].z * yv[c].z + xv[a].w * yv[c].w;
    }
    #pragma unroll
    for (int a = 0; a < 8; ++a) {
        int ii = ti + 16 * a + tx;
        float xn = nx[16 * a + tx];
        #pragma unroll
        for (int c = 0; c < 8; ++c) {
            int jj = tj + 16 * c + ty;
            float d = xn + ny[16 * c + ty] - 2.0f * acc[a][c];
            size_t idx = ((size_t)b * 512 + ((jj + ii) & 511)) * 512 + ii;
            DS[idx] = fmaxf(d, 0.0f) * C1;
        }
    }
}

// up[l] = x[l-1] via DPP (no LDS): row_shr:1 + row_bcast15 fixes lanes 16/32/48.
__device__ __forceinline__ float dpp_shift_up1(float x) {
    int xi = __float_as_int(x);
    int sh  = __builtin_amdgcn_update_dpp(xi, xi, 0x111, 0xF, 0xF, false); // row_shr:1
    int b15 = __builtin_amdgcn_update_dpp(xi, xi, 0x142, 0xF, 0xF, false); // row_bcast15
    int lane = (int)(threadIdx.x & 63);
    int r = ((lane & 15) == 0) ? b15 : sh;
    return __int_as_float(r);
}

// ---------------------------------------------------------------------------
// gram tile body (blocks 60..125): 4x4 segment tile, 512 threads / 8 waves.
// ---------------------------------------------------------------------------
__device__ void gram_body(const float* __restrict__ data, float* __restrict__ Gm, int f) {
    int bx = 0, rem = f;
    for (int q = 0; q < 11; ++q) { int c = 11 - q; if (rem < c) { bx = q; break; } rem -= c; }
    int by = bx + rem;
    int t = threadIdx.x;                 // 0..511
    int lane = t & 63, wv = t >> 6;      // 8 waves
    const float* pa[4];
    const float* pb[4];
    #pragma unroll
    for (int i = 0; i < 4; ++i) {
        int sa = bx * 4 + i;
        int sb = by * 4 + i;
        pa[i] = data + (size_t)((sa / SEGN) * STEP + (sa % SEGN)) * SEGD;
        pb[i] = data + (size_t)((sb / SEGN) * STEP + (sb % SEGN)) * SEGD;
    }
    float acc[16] = {};
    for (int d = t * 4; d < SEGD; d += 2048) {
        float4 ra[4], rb[4];
        #pragma unroll
        for (int i = 0; i < 4; ++i) ra[i] = *(const float4*)(pa[i] + d);
        #pragma unroll
        for (int i = 0; i < 4; ++i) rb[i] = *(const float4*)(pb[i] + d);
        #pragma unroll
        for (int i = 0; i < 4; ++i)
            #pragma unroll
            for (int jj = 0; jj < 4; ++jj)
                acc[i * 4 + jj] += ra[i].x * rb[jj].x + ra[i].y * rb[jj].y +
                                   ra[i].z * rb[jj].z + ra[i].w * rb[jj].w;
    }
    #pragma unroll
    for (int i = 0; i < 16; ++i)
        #pragma unroll
        for (int s = 32; s > 0; s >>= 1)
            acc[i] += __shfl_xor(acc[i], s);
    __shared__ float part[8][16];
    if (lane == 0)
        #pragma unroll
        for (int i = 0; i < 16; ++i) part[wv][i] = acc[i];
    __syncthreads();
    if (t < 16) {
        float s = 0.f;
        #pragma unroll
        for (int k = 0; k < 8; ++k) s += part[k][t];
        int a = bx * 4 + (t >> 2), c = by * 4 + (t & 3);
        Gm[a * NSEG + c] = s;
        Gm[c * NSEG + a] = s;
    }
}

// ---------------------------------------------------------------------------
// K2: soft-DTW (blocks 0..59: ONE problem per block, 8 waves, R=1 row/lane —
// 512 rows; wall = la+lb-2 steps, the true DP dependency length) + gram
// (blocks 60..125). Deferred-log cell: V = P - log2(s); P-recursion is pure
// min-plus (short chain), exp2s off-chain, renorm every 16 steps. 1.25-2
// waves/SIMD so chain/handoff stalls of one wave are filled by its SIMD-mate.
// Cross-wave: 7 tiers of write-once 64-bit (P,s) LDS slots, NaN sentinel.
// ---------------------------------------------------------------------------
__global__ __launch_bounds__(512) void dtw_gram_kernel(const float* __restrict__ DS,
                                                       const int* __restrict__ lens,
                                                       const float* __restrict__ data,
                                                       float* __restrict__ res,
                                                       float* __restrict__ Gm) {
    int blk = blockIdx.x;
    if (blk >= GRAM_BLK0) { gram_body(data, Gm, blk - GRAM_BLK0); return; }

    int b = blk;
    int w_ = b / M_OTH, m = b % M_OTH;
    int la = lens[w_ * STEP];
    int lb = lens[w_ * STEP + 1 + m];
    int tid = threadIdx.x;               // 0..511
    int W = tid >> 6, l = tid & 63, G = tid;   // G = row-1 (row = G+1)
    const float* Db = DS + (size_t)b * 512 * 512;

    __shared__ unsigned long long bnd[NTIER][BNDW];
    for (int k = tid; k < NTIER * BNDW; k += 512)
        ((unsigned long long*)bnd)[k] = SENT;
    __syncthreads();                     // only barrier on the DTW path

    int gstar = la - 1;                  // lane holding row la
    int tcap = la + lb - 2;              // step where (la, lb) is computed
    if (64 * W > gstar) return;          // wave has no rows <= la
    int gmax = min(64 * W + 63, gstar);
    int t0 = 64 * W;
    int tend = lb + gmax - 1;
    int needmax = lb + 64 * W - 1;       // last step lane0 needs a boundary (W>0)
    bool pub = (W < NTIER);

    // state (deferred-log pairs, V = P - log2 s):
    float p = BIGS, s = 1.f;             // R(G+1, j-1)
    float pC = (G == 0) ? 0.f : BIGS;    // R(G, j-1); R(0,0)=0 for lane G=0
    float sC = 1.f;
    float pA = BIGS, sA = 1.f;           // R(G, j) incoming
    float outp = 0.f, outs = 1.f;

    float ring[8];                       // D prefetch ring (static idx)
    #pragma unroll
    for (int k = 0; k < 8; ++k)
        ring[k] = Db[(size_t)(((t0 + k) & 511) * 512 + G)];
    unsigned long long ch[8];            // boundary chunk (static idx)
    #pragma unroll
    for (int k = 0; k < 8; ++k) ch[k] = SENT;

    const unsigned long long* bsrc = (W > 0) ? bnd[W - 1] : bnd[0];

    for (int t = t0; t <= tend; t += 8) {
        if (W > 0 && t <= needmax) {     // validate speculative chunk
            bool ok = (t + 7 <= needmax) &&
                      !__builtin_isnan(__int_as_float((int)(unsigned)ch[3])) &&
                      !__builtin_isnan(__int_as_float((int)(unsigned)ch[7]));
            if (!ok) {
                int lastIdx = min(t + 7, needmax);
                unsigned long long v = __hip_atomic_load(&bsrc[lastIdx], __ATOMIC_RELAXED,
                                                         __HIP_MEMORY_SCOPE_WORKGROUP);
                while (__builtin_isnan(__int_as_float((int)(unsigned)v))) {
                    __builtin_amdgcn_s_sleep(1);
                    v = __hip_atomic_load(&bsrc[lastIdx], __ATOMIC_RELAXED,
                                          __HIP_MEMORY_SCOPE_WORKGROUP);
                }
                __builtin_amdgcn_fence(__ATOMIC_ACQUIRE, "workgroup");
                #pragma unroll
                for (int k = 0; k < 8; ++k)
                    ch[k] = __hip_atomic_load(&bsrc[t + k], __ATOMIC_RELAXED,
                                              __HIP_MEMORY_SCOPE_WORKGROUP);
            }
        }
        #pragma unroll
        for (int k = 0; k < 8; ++k) {
            int tt = t + k;
            // A-input: lane0 takes the cross-wave boundary (or BIG for wave 0)
            float pAx = pA, sAx = sA;
            if (l == 0) {
                if (W > 0) {
                    pAx = __int_as_float((int)(unsigned)ch[k]);
                    sAx = __int_as_float((int)(unsigned)(ch[k] >> 32));
                } else { pAx = BIGS; sAx = 1.f; }
            }
            float D = ring[k];
            ring[k] = Db[(size_t)((((tt + 8) & 511)) * 512 + G)];
            // softmin in deferred-log form (P-chain: fmin+fadd only)
            float mbc = fminf(p, pC), xbc = fmaxf(p, pC);
            float ebc = __builtin_amdgcn_exp2f(mbc - xbc);            // off chain
            float E2  = (p <= pC) ? fmaf(ebc, sC, s) : fmaf(ebc, s, sC);
            float ref = fminf(pAx, mbc), mx = fmaxf(pAx, mbc);
            float e = __builtin_amdgcn_exp2f(ref - mx);               // off P-chain
            float sN = (pAx <= mbc) ? fmaf(e, E2, sAx) : fmaf(e, sAx, E2);
            float pN = D + ref;
            bool valid = (tt >= G);      // j = tt-G+1 >= 1 (j>L is garbage-safe)
            p = valid ? pN : p;
            s = valid ? sN : s;
            if (tt == tcap) {            // uniform branch
                if (G == gstar) { outp = p; outs = s; }
            }
            float upP = dpp_shift_up1(p);                // VALU-only lane shift
            float upS = dpp_shift_up1(s);
            if (pub && l == 63) {
                union { float2 f; unsigned long long u; } pk;
                pk.f = make_float2(p, s);                // P in low half
                __hip_atomic_store(&bnd[W][tt + 1], pk.u, __ATOMIC_RELAXED,
                                   __HIP_MEMORY_SCOPE_WORKGROUP);
            }
            pC = pAx; sC = sAx;
            pA = upP; sA = upS;          // lane0 overridden next step
        }
        if ((t & 8) != 0) {              // renormalize every 16 steps (s <= 3^16)
            p -= __builtin_amdgcn_logf(s);               // v_log_f32 = log2
            s = 1.0f;
        }
        if (W > 0) {                     // speculative next chunk (4 x b128 reads)
            const ull2_t* sp = (const ull2_t*)&bsrc[t + 8];
            ull2_t c0 = sp[0], c1 = sp[1], c2 = sp[2], c3 = sp[3];
            ch[0] = c0.x; ch[1] = c0.y; ch[2] = c1.x; ch[3] = c1.y;
            ch[4] = c2.x; ch[5] = c2.y; ch[6] = c3.x; ch[7] = c3.y;
        }
    }
    if (G == gstar)
        res[b] = (outp - __builtin_amdgcn_logf(outs)) * GLN2 / (float)(la + lb);
}

// ---------------------------------------------------------------------------
// K3: finalize — losses + 9 MMDs, wave-shuffle reductions.
// ---------------------------------------------------------------------------
__global__ __launch_bounds__(512) void finalize_kernel(const float* __restrict__ res,
                                                       const float* __restrict__ G,
                                                       float* __restrict__ out) {
    __shared__ float wpart[9][8];
    __shared__ float bws[9];
    __shared__ float mmds[9];
    __shared__ float wloss[NW];
    __shared__ int   wnzr[NW];
    int t = threadIdx.x, lane = t & 63, wv = t >> 6;

    if (t < NW) {
        int w = t;
        float dg[NG], dn[NF + NR];
        for (int g = 0; g < NG; ++g) dg[g] = res[w * M_OTH + g];
        for (int q2 = 0; q2 < NF + NR; ++q2) dn[q2] = res[w * M_OTH + NG + q2];
        float sum_s = 0.f, sum_r = 0.f;
        int nzs = 0, nzr = 0;
        for (int g = 0; g < NG; ++g) {
            for (int f = 0; f < NF; ++f) {
                float v = dg[g] + 1.0f - dn[f];
                if (v > 0.f) { sum_s += v; nzs++; }
            }
            for (int r = 0; r < NR; ++r) {
                float v = dg[g] + 1.5f - dn[NF + r];
                if (v > 0.f) { sum_r += v; nzr++; }
            }
        }
        float ca = (dg[0] + dg[1] + dg[2] + dg[3] + dg[4]) / 5.0f;
        float cb = (dn[0] + dn[1] + dn[2] + dn[3]) * 0.25f;
        float intra = 0.f;
        for (int g = 0; g < NG; ++g) intra += dg[g] - ca;
        float inter = fmaxf(0.f, 1.0f - fabsf(ca - cb));
        float lv = (sum_s + sum_r) / (float)(nzs + nzr + 1);
        float bce = 0.f;
        for (int r = 0; r < NR; ++r) {
            float x = dn[NF + r] - dg[0];
            float ls = (x >= 0.f) ? -log1pf(expf(-x)) : (x - log1pf(expf(x)));
            bce += ls;
        }
        bce = -bce / 5.0f;
        wloss[w] = bce + lv + intra * 0.01f + inter * 0.01f;
        wnzr[w] = nzr;
    }

    const int pi[9] = {0, 0, 0, 1, 1, 2, 2, 3, 3};
    const int pj[9] = {1, 2, 3, 2, 3, 1, 3, 1, 2};
    int pp = t / 22, qq = t % 22;
    bool act = t < 484;
    float l2v[9];
    #pragma unroll
    for (int p = 0; p < 9; ++p) {
        float v = 0.f;
        if (act) {
            int wi = pi[p], wj = pj[p];
            int gp = (pp < 11) ? wi * SEGN + pp : wj * SEGN + (pp - 11);
            int gq = (qq < 11) ? wi * SEGN + qq : wj * SEGN + (qq - 11);
            v = fmaxf(G[gp * NSEG + gp] + G[gq * NSEG + gq] - 2.f * G[gp * NSEG + gq], 0.f);
        }
        l2v[p] = v;
    }
    #pragma unroll
    for (int p = 0; p < 9; ++p) {
        float r = l2v[p];
        #pragma unroll
        for (int s = 32; s > 0; s >>= 1) r += __shfl_xor(r, s);
        if (lane == 0) wpart[p][wv] = r;
    }
    __syncthreads();
    if (t < 9) {
        float s = 0.f;
        #pragma unroll
        for (int k = 0; k < 8; ++k) s += wpart[t][k];
        bws[t] = s * (1.0f / 462.0f) * 0.25f;
    }
    __syncthreads();
    float sgn = ((pp < 11) == (qq < 11)) ? 1.f : -1.f;
    #pragma unroll
    for (int p = 0; p < 9; ++p) {
        float kv = 0.f;
        if (act) {
            float x = -l2v[p] / bws[p];
            kv = sgn * (__expf(x) + __expf(x * 0.5f) + __expf(x * 0.25f) +
                        __expf(x * 0.125f) + __expf(x * 0.0625f));
        }
        #pragma unroll
        for (int s = 32; s > 0; s >>= 1) kv += __shfl_xor(kv, s);
        if (lane == 0) wpart[p][wv] = kv;
    }
    __syncthreads();
    if (t < 9) {
        float s = 0.f;
        #pragma unroll
        for (int k = 0; k < 8; ++k) s += wpart[t][k];
        mmds[t] = s / 121.0f;
    }
    __syncthreads();
    if (t == 0) {
        float loss = 0.25f * (wloss[0] + wloss[1] + wloss[2] + wloss[3]);
        float mx = 0.f;
        for (int p = 0; p < 9; ++p) mx = fmaxf(mx, mmds[p]);
        out[0] = loss + 0.1f * mx;
        out[1] = (float)(wnzr[0] + wnzr[1] + wnzr[2] + wnzr[3]);
    }
}

// ---------------------------------------------------------------------------
extern "C" void kernel_launch(void* const* d_in, const int* in_sizes, int n_in,
                              void* d_out, int out_size, void* d_ws, size_t ws_size,
                              hipStream_t stream) {
    const float* data = (const float*)d_in[0];
    const int* lens = (const int*)d_in[1];

    float* DS  = (float*)d_ws;                               // 60*512*512 floats
    float* res = DS + (size_t)NB * 512 * 512;                // 60 floats
    float* G   = res + 64;                                   // 44*44 floats
    float* out = (float*)d_out;

    dim3 g1(4, 4, NB), b1(16, 16);
    sqdist_kernel<<<g1, b1, 0, stream>>>(data, lens, DS);
    dtw_gram_kernel<<<GRAM_BLK0 + 66, 512, 0, stream>>>(DS, lens, data, res, G);
    finalize_kernel<<<1, 512, 0, stream>>>(res, G, out);
}